// Round 1
// baseline (1682.978 us; speedup 1.0000x reference)
//
#include <hip/hip_runtime.h>
#include <hip/hip_bf16.h>

// Problem constants (from reference)
#define BB 8
#define TT 16
#define NNODE 10000
#define FF 64
#define HH 64
#define EE 1000000
#define MM 80000      // BB * NNODE
#define NCLS 3
#define NPB 2000      // nodes per block in reduce kernel (40 blocks * 2000 = 80000)

// ---------------------------------------------------------------------------
// Kernel A: degree count per timestep.  deg[tloc][dst] += 1
// ---------------------------------------------------------------------------
__global__ __launch_bounds__(256) void k_deg(const int* __restrict__ ei,
                                             float* __restrict__ deg, int t0) {
    int tloc = blockIdx.y;
    int e = blockIdx.x * 256 + threadIdx.x;
    if (e >= EE) return;
    int tg = t0 + tloc;
    int dst = ei[(size_t)tg * 2 * EE + EE + e];
    atomicAdd(&deg[(size_t)tloc * MM + dst], 1.0f);
}

// ---------------------------------------------------------------------------
// Kernel A2: deg -> dinv in place.  dinv = rsqrt(deg_count + 1)
// ---------------------------------------------------------------------------
__global__ __launch_bounds__(256) void k_dinv(float* __restrict__ deg, int n) {
    int i = blockIdx.x * 256 + threadIdx.x;
    if (i < n) deg[i] = rsqrtf(deg[i] + 1.0f);
}

// ---------------------------------------------------------------------------
// Kernel B: edge scatter.  a[tloc][src][b(dst)] += dinv[dst]
// ---------------------------------------------------------------------------
__global__ __launch_bounds__(256) void k_edge(const int* __restrict__ ei,
                                              const float* __restrict__ dinv,
                                              float* __restrict__ a, int t0) {
    int tloc = blockIdx.y;
    int e = blockIdx.x * 256 + threadIdx.x;
    if (e >= EE) return;
    int tg = t0 + tloc;
    const int* base = ei + (size_t)tg * 2 * EE;
    int src = base[e];
    int dst = base[EE + e];
    int b = dst / NNODE;
    float dv = dinv[(size_t)tloc * MM + dst];
    atomicAdd(&a[((size_t)tloc * MM + src) * BB + b], dv);
}

// ---------------------------------------------------------------------------
// Kernel D: weighted feature reduction.
//   y[tg][b][f] += sum_j graph_seq[t, j, f] * w_b[j]
//   w_b[j] = dinv[j] * (a[j][b] + (b == j/N ? dinv[j] : 0))
// Wave layout: 4 nodes per wave-iteration; 16 lanes (float4) per node row.
// ---------------------------------------------------------------------------
__global__ __launch_bounds__(256) void k_reduce(const float* __restrict__ g,
                                                const float* __restrict__ dinv,
                                                const float* __restrict__ a,
                                                float* __restrict__ y, int t0) {
    int tloc = blockIdx.y;
    int tg = t0 + tloc;
    int j0 = blockIdx.x * NPB;
    int lane = threadIdx.x & 63;
    int wave = threadIdx.x >> 6;
    int sub = lane >> 4;          // which of 4 nodes this quarter-wave handles
    int f0 = (lane & 15) << 2;    // feature base (float4)

    const float* dv_t = dinv + (size_t)tloc * MM;
    const float* a_t  = a + (size_t)tloc * MM * BB;

    float acc[BB][4];
#pragma unroll
    for (int b = 0; b < BB; b++)
#pragma unroll
        for (int q = 0; q < 4; q++) acc[b][q] = 0.0f;

    const int ngroups = NPB / 4;  // 500
    for (int gidx = wave; gidx < ngroups; gidx += 4) {
        int j = j0 + gidx * 4 + sub;
        int bj = j / NNODE;
        int nj = j - bj * NNODE;
        const float4 g4 = *(const float4*)(g + ((size_t)(bj * TT + tg) * NNODE + nj) * FF + f0);
        float dvj = dv_t[j];
        const float4 a0 = *(const float4*)(a_t + (size_t)j * BB);
        const float4 a1 = *(const float4*)(a_t + (size_t)j * BB + 4);
        float av[BB] = {a0.x, a0.y, a0.z, a0.w, a1.x, a1.y, a1.z, a1.w};
        float wv[BB];
#pragma unroll
        for (int b = 0; b < BB; b++)
            wv[b] = dvj * (av[b] + (b == bj ? dvj : 0.0f));
#pragma unroll
        for (int b = 0; b < BB; b++) {
            acc[b][0] = fmaf(g4.x, wv[b], acc[b][0]);
            acc[b][1] = fmaf(g4.y, wv[b], acc[b][1]);
            acc[b][2] = fmaf(g4.z, wv[b], acc[b][2]);
            acc[b][3] = fmaf(g4.w, wv[b], acc[b][3]);
        }
    }

    // reduce across the 4 quarter-waves (lanes sharing same f0)
#pragma unroll
    for (int b = 0; b < BB; b++)
#pragma unroll
        for (int q = 0; q < 4; q++) {
            float v = acc[b][q];
            v += __shfl_xor(v, 16);
            v += __shfl_xor(v, 32);
            acc[b][q] = v;
        }

    __shared__ float red[4][BB * FF];
    if (sub == 0) {
#pragma unroll
        for (int b = 0; b < BB; b++)
#pragma unroll
            for (int q = 0; q < 4; q++)
                red[wave][b * FF + f0 + q] = acc[b][q];
    }
    __syncthreads();

    for (int idx = threadIdx.x; idx < BB * FF; idx += 256) {
        float s = red[0][idx] + red[1][idx] + red[2][idx] + red[3][idx];
        atomicAdd(&y[(size_t)tg * (BB * FF) + idx], s);
    }
}

// ---------------------------------------------------------------------------
// Kernel E: per-batch pooled projection + LSTM scan + final FC.
// One block per batch element (the 8 LSTMs are independent).
// Thread r (0..255) owns gate-row r; W_ih/W_hh rows cached in registers.
// ---------------------------------------------------------------------------
__global__ __launch_bounds__(256) void k_lstm(const float* __restrict__ y,
                                              const float* __restrict__ Wg,
                                              const float* __restrict__ bg,
                                              const float* __restrict__ Wih,
                                              const float* __restrict__ Whh,
                                              const float* __restrict__ bih,
                                              const float* __restrict__ bhh,
                                              const float* __restrict__ Wfc,
                                              const float* __restrict__ bfc,
                                              float* __restrict__ out) {
    int b = blockIdx.x;
    int r = threadIdx.x;

    __shared__ float xs[TT][HH];
    __shared__ float hs[HH], cs[HH], zs[4 * HH];

    // pooled[t][h] = (1/N) * sum_f y[t][b][f] * Wg[f][h] + bg[h]
    for (int idx = r; idx < TT * HH; idx += 256) {
        int t = idx >> 6, h = idx & 63;
        const float* yt = y + ((size_t)t * BB + b) * FF;
        float s = 0.0f;
#pragma unroll
        for (int f = 0; f < FF; f++) s = fmaf(yt[f], Wg[f * HH + h], s);
        xs[t][h] = s * (1.0f / NNODE) + bg[h];
    }

    // cache this thread's gate-row weights in registers
    float wih[HH], whh[HH];
#pragma unroll
    for (int k = 0; k < HH; k++) {
        wih[k] = Wih[r * HH + k];
        whh[k] = Whh[r * HH + k];
    }
    float bias = bih[r] + bhh[r];

    if (r < HH) { hs[r] = 0.0f; cs[r] = 0.0f; }
    __syncthreads();

    for (int t = 0; t < TT; t++) {
        float acc = bias;
#pragma unroll
        for (int k = 0; k < HH; k++)
            acc = fmaf(wih[k], xs[t][k], fmaf(whh[k], hs[k], acc));
        zs[r] = acc;
        __syncthreads();
        if (r < HH) {
            float iv = zs[r], fv = zs[HH + r], gv = zs[2 * HH + r], ov = zs[3 * HH + r];
            float si = 1.0f / (1.0f + expf(-iv));
            float sf = 1.0f / (1.0f + expf(-fv));
            float so = 1.0f / (1.0f + expf(-ov));
            float c = sf * cs[r] + si * tanhf(gv);
            cs[r] = c;
            hs[r] = so * tanhf(c);
        }
        __syncthreads();
    }

    if (r < NCLS) {
        float s = bfc[r];
#pragma unroll
        for (int k = 0; k < HH; k++) s = fmaf(hs[k], Wfc[r * HH + k], s);
        out[b * NCLS + r] = s;
    }
}

// ---------------------------------------------------------------------------
extern "C" void kernel_launch(void* const* d_in, const int* in_sizes, int n_in,
                              void* d_out, int out_size, void* d_ws, size_t ws_size,
                              hipStream_t stream) {
    const float* g   = (const float*)d_in[0];
    const int*   ei  = (const int*)d_in[1];
    const float* Wg  = (const float*)d_in[2];
    const float* bg  = (const float*)d_in[3];
    const float* Wih = (const float*)d_in[4];
    const float* Whh = (const float*)d_in[5];
    const float* bih = (const float*)d_in[6];
    const float* bhh = (const float*)d_in[7];
    const float* Wfc = (const float*)d_in[8];
    const float* bfc = (const float*)d_in[9];
    float* out = (float*)d_out;

    char* ws = (char*)d_ws;
    float* y = (float*)ws;                                  // [T][B][F] accumulators
    const size_t yBytes = (size_t)TT * BB * FF * sizeof(float);

    // chunk timesteps so deg (M floats) + a (M*8 floats) fit in workspace
    size_t avail = (ws_size > yBytes) ? (ws_size - yBytes) : 0;
    int Tc = (int)(avail / ((size_t)MM * sizeof(float) * (1 + BB)));
    if (Tc > TT) Tc = TT;
    if (Tc < 1) Tc = 1;

    float* deg = (float*)(ws + yBytes);
    float* a   = (float*)(ws + yBytes + (size_t)Tc * MM * sizeof(float));

    hipMemsetAsync(y, 0, yBytes, stream);

    for (int t0 = 0; t0 < TT; t0 += Tc) {
        int tc = (TT - t0 < Tc) ? (TT - t0) : Tc;
        hipMemsetAsync(deg, 0, (size_t)tc * MM * sizeof(float), stream);
        hipMemsetAsync(a, 0, (size_t)tc * MM * BB * sizeof(float), stream);

        dim3 gE((EE + 255) / 256, tc);
        k_deg<<<gE, 256, 0, stream>>>(ei, deg, t0);

        int nd = tc * MM;
        k_dinv<<<(nd + 255) / 256, 256, 0, stream>>>(deg, nd);

        k_edge<<<gE, 256, 0, stream>>>(ei, deg, a, t0);

        dim3 gR(MM / NPB, tc);
        k_reduce<<<gR, 256, 0, stream>>>(g, deg, a, y, t0);
    }

    k_lstm<<<BB, 256, 0, stream>>>(y, Wg, bg, Wih, Whh, bih, bhh, Wfc, bfc, out);
}

// Round 2
// 557.543 us; speedup vs baseline: 3.0186x; 3.0186x over previous
//
#include <hip/hip_runtime.h>
#include <hip/hip_bf16.h>

// Problem constants
#define BB 8
#define TT 16
#define NNODE 10000
#define FF 64
#define HH 64
#define EE 1000000
#define MM 80000      // BB * NNODE
#define NCLS 3

#define NCHUNK 32     // src chunks per timestep
#define NPC 2500      // nodes per chunk (NCHUNK*NPC == MM); 10000%2500==0 -> b uniform per chunk
#define CAPB 36000    // bucket capacity (expected 31250, sigma~174)
#define NSEG_H 16     // histogram edge segments
#define NSEG_P 64     // partition edge segments
#define HW 20000      // histogram words (u8-packed: 4 bins/word, 80000 bins)
#define STG 384       // staging entries per bucket in k_part

// ---------------------------------------------------------------------------
// Kernel 1: per-timestep dst histogram, LDS-privatized, u8-packed.
// grid (NSEG_H, tc). Writes dense partials (no global atomics).
// ---------------------------------------------------------------------------
__global__ __launch_bounds__(256) void k_hist(const int* __restrict__ ei,
                                              unsigned int* __restrict__ part, int t0) {
    __shared__ unsigned int h[HW];   // 80 KB
    int seg = blockIdx.x, tloc = blockIdx.y, tg = t0 + tloc;
    for (int i = threadIdx.x; i < HW; i += 256) h[i] = 0u;
    __syncthreads();
    const int* dstp = ei + (size_t)tg * 2 * EE + EE + (size_t)seg * (EE / NSEG_H);
    for (int i = threadIdx.x; i < EE / NSEG_H; i += 256) {
        unsigned int d = (unsigned int)dstp[i];
        atomicAdd(&h[d >> 2], 1u << ((d & 3u) * 8u));
    }
    __syncthreads();
    unsigned int* outp = part + ((size_t)tloc * NSEG_H + seg) * HW;
    for (int i = threadIdx.x; i < HW; i += 256) outp[i] = h[i];
}

// ---------------------------------------------------------------------------
// Kernel 2: merge histogram partials -> dinv = rsqrt(deg+1).
// Word-summing is safe: per-byte totals (node degree <= ~60) never carry.
// ---------------------------------------------------------------------------
__global__ __launch_bounds__(256) void k_mdeg(const unsigned int* __restrict__ part,
                                              float* __restrict__ dinv) {
    int w = blockIdx.x * 256 + threadIdx.x;
    int tloc = blockIdx.y;
    if (w >= HW) return;
    const unsigned int* p = part + (size_t)tloc * NSEG_H * HW;
    unsigned int s = 0;
#pragma unroll
    for (int k = 0; k < NSEG_H; k++) s += p[(size_t)k * HW + w];
    float4 r;
    r.x = rsqrtf((float)(s & 255u) + 1.0f);
    r.y = rsqrtf((float)((s >> 8) & 255u) + 1.0f);
    r.z = rsqrtf((float)((s >> 16) & 255u) + 1.0f);
    r.w = rsqrtf((float)((s >> 24) & 255u) + 1.0f);
    *(float4*)(dinv + (size_t)tloc * MM + (size_t)w * 4) = r;
}

// ---------------------------------------------------------------------------
// Kernel 3: partition edges by src-chunk. Record = (src_off<<17)|dst (4B).
// LDS staging -> coalesced global writes; global atomics only on cursors.
// grid (NSEG_P, tc).
// ---------------------------------------------------------------------------
__global__ __launch_bounds__(256) void k_part(const int* __restrict__ ei,
                                              unsigned int* __restrict__ buck,
                                              unsigned int* __restrict__ gcur, int t0) {
    __shared__ unsigned int stg[NCHUNK * STG];   // 48 KB
    __shared__ unsigned int cur[NCHUNK];
    int seg = blockIdx.x, tloc = blockIdx.y, tg = t0 + tloc;
    if (threadIdx.x < NCHUNK) cur[threadIdx.x] = 0u;
    __syncthreads();
    const int* srcp = ei + (size_t)tg * 2 * EE;
    const int* dstp = srcp + EE;
    const int e0 = seg * (EE / NSEG_P);
    const int ne = EE / NSEG_P;                  // 15625
    unsigned int* gc = gcur + tloc * NCHUNK;
    unsigned int* bk = buck + (size_t)tloc * NCHUNK * CAPB;
    int wave = threadIdx.x >> 6, lane = threadIdx.x & 63;

    for (int base = 0; base < ne; base += 256) {
        int i = base + threadIdx.x;
        if (i < ne) {
            unsigned int s = (unsigned int)srcp[e0 + i];
            unsigned int d = (unsigned int)dstp[e0 + i];
            unsigned int ck = (unsigned int)(((unsigned long long)s * 1717987ull) >> 32); // s/2500
            unsigned int so = s - ck * NPC;
            unsigned int p = atomicAdd(&cur[ck], 1u);   // invariant: p < STG
            stg[ck * STG + p] = (so << 17) | d;
        }
        __syncthreads();
        bool last = (base + 256 >= ne);
        // wave w owns chunks [w*8, w*8+8)
#pragma unroll
        for (int k = 0; k < 8; k++) {
            int ck = wave * 8 + k;
            unsigned int n = cur[ck];
            if (n >= 128u || (last && n > 0u)) {
                unsigned int gp = 0;
                if (lane == 0) gp = atomicAdd(&gc[ck], n);
                gp = (unsigned int)__shfl((int)gp, 0);
                unsigned int room = (gp < CAPB) ? (CAPB - gp) : 0u;
                unsigned int nw = n < room ? n : room;
                for (unsigned int j = lane; j < nw; j += 64)
                    bk[(size_t)ck * CAPB + gp + j] = stg[ck * STG + j];
                if (lane == 0) cur[ck] = 0u;
            }
        }
        __syncthreads();
    }
}

// ---------------------------------------------------------------------------
// Kernel 4 (fused): build a[src][b] chunk in LDS from bucket records, then
// stream the chunk's g rows computing y[t][b][f] partials. a never hits HBM.
// grid (NCHUNK, tc). LDS 80 KB -> 2 blocks/CU.
// ---------------------------------------------------------------------------
__global__ __launch_bounds__(256) void k_scat(const float* __restrict__ g,
                                              const float* __restrict__ dinv,
                                              const unsigned int* __restrict__ buck,
                                              const unsigned int* __restrict__ gcur,
                                              float* __restrict__ y, int t0) {
    __shared__ float a[NPC * BB];   // 80 KB
    int c = blockIdx.x, tloc = blockIdx.y, tg = t0 + tloc;
    for (int i = threadIdx.x; i < NPC * BB; i += 256) a[i] = 0.0f;
    __syncthreads();

    const float* dv = dinv + (size_t)tloc * MM;
    unsigned int n = gcur[tloc * NCHUNK + c];
    if (n > CAPB) n = CAPB;
    const unsigned int* bk = buck + ((size_t)tloc * NCHUNK + c) * CAPB;

    // build phase: 4 records per lane per iter for ILP
    unsigned int n4 = n >> 2;
    for (unsigned int i = threadIdx.x; i < n4; i += 256) {
        uint4 r = ((const uint4*)bk)[i];
        unsigned int rec[4] = {r.x, r.y, r.z, r.w};
#pragma unroll
        for (int k = 0; k < 4; k++) {
            unsigned int d = rec[k] & 0x1FFFFu;
            unsigned int so = rec[k] >> 17;
            unsigned int b = (unsigned int)(((unsigned long long)d * 429497ull) >> 32); // d/10000
            atomicAdd(&a[so * BB + b], dv[d]);
        }
    }
    {
        unsigned int i = (n4 << 2) + threadIdx.x;
        if (i < n) {
            unsigned int rec = bk[i];
            unsigned int d = rec & 0x1FFFFu;
            unsigned int so = rec >> 17;
            unsigned int b = (unsigned int)(((unsigned long long)d * 429497ull) >> 32);
            atomicAdd(&a[so * BB + b], dv[d]);
        }
    }
    __syncthreads();

    // reduce phase: stream g rows for this chunk
    int lane = threadIdx.x & 63;
    int wave = threadIdx.x >> 6;
    int sub = lane >> 4;            // node within group of 4
    int f0 = (lane & 15) << 2;      // float4 feature base
    int b_c = c >> 2;               // batch of every node in this chunk (10000%2500==0)
    const size_t base_g = ((size_t)(b_c * TT + tg) * NNODE + (size_t)(c & 3) * NPC) * FF;
    const float* dvc = dv + (size_t)c * NPC;

    float acc[BB][4];
#pragma unroll
    for (int b = 0; b < BB; b++)
#pragma unroll
        for (int q = 0; q < 4; q++) acc[b][q] = 0.0f;

    for (int gi = wave; gi < NPC / 4; gi += 4) {
        int joff = gi * 4 + sub;
        float dvj = dvc[joff];
        const float4 g4 = *(const float4*)(g + base_g + (size_t)joff * FF + f0);
        const float4 a0 = *(const float4*)(&a[joff * BB]);
        const float4 a1 = *(const float4*)(&a[joff * BB + 4]);
        float av[BB] = {a0.x, a0.y, a0.z, a0.w, a1.x, a1.y, a1.z, a1.w};
        float wv[BB];
#pragma unroll
        for (int b = 0; b < BB; b++)
            wv[b] = dvj * (av[b] + (b == b_c ? dvj : 0.0f));
#pragma unroll
        for (int b = 0; b < BB; b++) {
            acc[b][0] = fmaf(g4.x, wv[b], acc[b][0]);
            acc[b][1] = fmaf(g4.y, wv[b], acc[b][1]);
            acc[b][2] = fmaf(g4.z, wv[b], acc[b][2]);
            acc[b][3] = fmaf(g4.w, wv[b], acc[b][3]);
        }
    }

    __syncthreads();  // all a-reads done; reuse a[] as reduction scratch
#pragma unroll
    for (int b = 0; b < BB; b++)
#pragma unroll
        for (int q = 0; q < 4; q++) {
            float v = acc[b][q];
            v += __shfl_xor(v, 16);
            v += __shfl_xor(v, 32);
            acc[b][q] = v;
        }
    if (sub == 0) {
#pragma unroll
        for (int b = 0; b < BB; b++)
#pragma unroll
            for (int q = 0; q < 4; q++)
                a[wave * (BB * FF) + b * FF + f0 + q] = acc[b][q];
    }
    __syncthreads();
    for (int idx = threadIdx.x; idx < BB * FF; idx += 256) {
        float s = a[idx] + a[BB * FF + idx] + a[2 * BB * FF + idx] + a[3 * BB * FF + idx];
        atomicAdd(&y[(size_t)tg * (BB * FF) + idx], s);
    }
}

// ---------------------------------------------------------------------------
// Kernel 5: pooled projection + LSTM + FC (verified in round 1, unchanged).
// ---------------------------------------------------------------------------
__global__ __launch_bounds__(256) void k_lstm(const float* __restrict__ y,
                                              const float* __restrict__ Wg,
                                              const float* __restrict__ bg,
                                              const float* __restrict__ Wih,
                                              const float* __restrict__ Whh,
                                              const float* __restrict__ bih,
                                              const float* __restrict__ bhh,
                                              const float* __restrict__ Wfc,
                                              const float* __restrict__ bfc,
                                              float* __restrict__ out) {
    int b = blockIdx.x;
    int r = threadIdx.x;

    __shared__ float xs[TT][HH];
    __shared__ float hs[HH], cs[HH], zs[4 * HH];

    for (int idx = r; idx < TT * HH; idx += 256) {
        int t = idx >> 6, h = idx & 63;
        const float* yt = y + ((size_t)t * BB + b) * FF;
        float s = 0.0f;
#pragma unroll
        for (int f = 0; f < FF; f++) s = fmaf(yt[f], Wg[f * HH + h], s);
        xs[t][h] = s * (1.0f / NNODE) + bg[h];
    }

    float wih[HH], whh[HH];
#pragma unroll
    for (int k = 0; k < HH; k++) {
        wih[k] = Wih[r * HH + k];
        whh[k] = Whh[r * HH + k];
    }
    float bias = bih[r] + bhh[r];

    if (r < HH) { hs[r] = 0.0f; cs[r] = 0.0f; }
    __syncthreads();

    for (int t = 0; t < TT; t++) {
        float acc = bias;
#pragma unroll
        for (int k = 0; k < HH; k++)
            acc = fmaf(wih[k], xs[t][k], fmaf(whh[k], hs[k], acc));
        zs[r] = acc;
        __syncthreads();
        if (r < HH) {
            float iv = zs[r], fv = zs[HH + r], gv = zs[2 * HH + r], ov = zs[3 * HH + r];
            float si = 1.0f / (1.0f + expf(-iv));
            float sf = 1.0f / (1.0f + expf(-fv));
            float so = 1.0f / (1.0f + expf(-ov));
            float cc = sf * cs[r] + si * tanhf(gv);
            cs[r] = cc;
            hs[r] = so * tanhf(cc);
        }
        __syncthreads();
    }

    if (r < NCLS) {
        float s = bfc[r];
#pragma unroll
        for (int k = 0; k < HH; k++) s = fmaf(hs[k], Wfc[r * HH + k], s);
        out[b * NCLS + r] = s;
    }
}

// ---------------------------------------------------------------------------
extern "C" void kernel_launch(void* const* d_in, const int* in_sizes, int n_in,
                              void* d_out, int out_size, void* d_ws, size_t ws_size,
                              hipStream_t stream) {
    const float* g   = (const float*)d_in[0];
    const int*   ei  = (const int*)d_in[1];
    const float* Wg  = (const float*)d_in[2];
    const float* bg  = (const float*)d_in[3];
    const float* Wih = (const float*)d_in[4];
    const float* Whh = (const float*)d_in[5];
    const float* bih = (const float*)d_in[6];
    const float* bhh = (const float*)d_in[7];
    const float* Wfc = (const float*)d_in[8];
    const float* bfc = (const float*)d_in[9];
    float* out = (float*)d_out;

    char* ws = (char*)d_ws;
    float* y = (float*)ws;                          // [T][B][F]
    const size_t yBytes = 32768;                    // 16*8*64*4 padded to 32KB

    const size_t sz_dinv = (size_t)MM * 4;          // 320 KB
    const size_t sz_part = (size_t)NSEG_H * HW * 4; // 1.28 MB
    const size_t sz_buck = (size_t)NCHUNK * CAPB * 4; // 4.608 MB
    const size_t sz_gcur = (size_t)NCHUNK * 4;
    const size_t per_t = sz_dinv + sz_part + sz_buck + sz_gcur;

    size_t avail = (ws_size > yBytes) ? ws_size - yBytes : 0;
    int Tg = (int)(avail / per_t);
    if (Tg > TT) Tg = TT;
    if (Tg < 1) Tg = 1;

    float* dinv        = (float*)(ws + yBytes);
    unsigned int* part = (unsigned int*)(ws + yBytes + (size_t)Tg * sz_dinv);
    unsigned int* buck = (unsigned int*)(ws + yBytes + (size_t)Tg * (sz_dinv + sz_part));
    unsigned int* gcur = (unsigned int*)(ws + yBytes + (size_t)Tg * (sz_dinv + sz_part + sz_buck));

    hipMemsetAsync(y, 0, (size_t)TT * BB * FF * sizeof(float), stream);

    for (int t0 = 0; t0 < TT; t0 += Tg) {
        int tc = (TT - t0 < Tg) ? (TT - t0) : Tg;
        hipMemsetAsync(gcur, 0, (size_t)tc * NCHUNK * 4, stream);

        dim3 gh(NSEG_H, tc);
        k_hist<<<gh, 256, 0, stream>>>(ei, part, t0);

        dim3 gm((HW + 255) / 256, tc);
        k_mdeg<<<gm, 256, 0, stream>>>(part, dinv);

        dim3 gp(NSEG_P, tc);
        k_part<<<gp, 256, 0, stream>>>(ei, buck, gcur, t0);

        dim3 gs(NCHUNK, tc);
        k_scat<<<gs, 256, 0, stream>>>(g, dinv, buck, gcur, y, t0);
    }

    k_lstm<<<BB, 256, 0, stream>>>(y, Wg, bg, Wih, Whh, bih, bhh, Wfc, bfc, out);
}

// Round 3
// 471.964 us; speedup vs baseline: 3.5659x; 1.1813x over previous
//
#include <hip/hip_runtime.h>
#include <hip/hip_bf16.h>

// Problem constants
#define BB 8
#define TT 16
#define NNODE 10000
#define FF 64
#define HH 64
#define EE 1000000
#define MM 80000      // BB * NNODE
#define NCLS 3

#define NCHUNK 32     // src chunks per timestep
#define NPC 2500      // nodes per chunk (NCHUNK*NPC == MM)
#define CAPB 36032    // bucket capacity (expected 31250, sigma~174; 64-aligned)
#define NSEG_H 16     // histogram edge segments (62500 edges each, uint4-divisible)
#define HW 20000      // histogram words (u8-packed: 4 bins/word = 80000 bins)
#define NSEG_B 32     // k_part blocks per timestep (x4 waves = 128 wave-segments/t)
#define EPW 7813      // edges per wave-segment: ceil(1e6 / 128)
#define WCAP 128      // wave-private staging capacity per chunk

// ---------------------------------------------------------------------------
// Kernel 1: per-timestep dst histogram, LDS-privatized, u8-packed, uint4 loads.
// grid (NSEG_H, tc). Dense partial writeback (no global atomics).
// ---------------------------------------------------------------------------
__global__ __launch_bounds__(256) void k_hist(const int* __restrict__ ei,
                                              unsigned int* __restrict__ part, int t0) {
    __shared__ unsigned int h[HW];   // 80 KB
    int seg = blockIdx.x, tloc = blockIdx.y, tg = t0 + tloc;
    for (int i = threadIdx.x; i < HW; i += 256) h[i] = 0u;
    __syncthreads();
    const uint4* dstp = (const uint4*)(ei + (size_t)tg * 2 * EE + EE
                                       + (size_t)seg * (EE / NSEG_H));
    for (int i = threadIdx.x; i < (EE / NSEG_H) / 4; i += 256) {
        uint4 d4 = dstp[i];
        atomicAdd(&h[d4.x >> 2], 1u << ((d4.x & 3u) * 8u));
        atomicAdd(&h[d4.y >> 2], 1u << ((d4.y & 3u) * 8u));
        atomicAdd(&h[d4.z >> 2], 1u << ((d4.z & 3u) * 8u));
        atomicAdd(&h[d4.w >> 2], 1u << ((d4.w & 3u) * 8u));
    }
    __syncthreads();
    unsigned int* outp = part + ((size_t)tloc * NSEG_H + seg) * HW;
    for (int i = threadIdx.x; i < HW; i += 256) outp[i] = h[i];
}

// ---------------------------------------------------------------------------
// Kernel 2: merge histogram partials -> dinv = rsqrt(deg+1).
// Word-summing safe: per-byte totals (max node degree ~50) never carry.
// ---------------------------------------------------------------------------
__global__ __launch_bounds__(256) void k_mdeg(const unsigned int* __restrict__ part,
                                              float* __restrict__ dinv) {
    int w = blockIdx.x * 256 + threadIdx.x;
    int tloc = blockIdx.y;
    if (w >= HW) return;
    const unsigned int* p = part + (size_t)tloc * NSEG_H * HW;
    unsigned int s = 0;
#pragma unroll
    for (int k = 0; k < NSEG_H; k++) s += p[(size_t)k * HW + w];
    float4 r;
    r.x = rsqrtf((float)(s & 255u) + 1.0f);
    r.y = rsqrtf((float)((s >> 8) & 255u) + 1.0f);
    r.z = rsqrtf((float)((s >> 16) & 255u) + 1.0f);
    r.w = rsqrtf((float)((s >> 24) & 255u) + 1.0f);
    *(float4*)(dinv + (size_t)tloc * MM + (size_t)w * 4) = r;
}

// ---------------------------------------------------------------------------
// Kernel 3: barrier-free edge partition. Each WAVE owns a private staging
// region (32 chunks x 128 entries) + private cursors -> zero __syncthreads,
// wave-local LDS atomics only. Flush = 1 global cursor atomic per ~64 records
// + coalesced append. Record = (src_off<<17)|dst.
// grid (NSEG_B, tc), 256 threads (4 independent waves). LDS 66 KB -> 2 blk/CU.
// ---------------------------------------------------------------------------
__global__ __launch_bounds__(256) void k_part(const int* __restrict__ ei,
                                              unsigned int* __restrict__ buck,
                                              unsigned int* __restrict__ gcur, int t0) {
    __shared__ unsigned int stg[4][NCHUNK][WCAP];   // 64 KB
    __shared__ unsigned int cur[4][NCHUNK];         // 512 B
    int wave = threadIdx.x >> 6, lane = threadIdx.x & 63;
    int tloc = blockIdx.y, tg = t0 + tloc;
    if (lane < NCHUNK) cur[wave][lane] = 0u;        // wave-private init, no barrier

    int ws = blockIdx.x * 4 + wave;                 // wave-segment id within t
    int e0 = ws * EPW;
    int e1 = e0 + EPW; if (e1 > EE) e1 = EE;
    const int* srcp = ei + (size_t)tg * 2 * EE;
    const int* dstp = srcp + EE;
    unsigned int* gc = gcur + tloc * NCHUNK;
    unsigned int* bk = buck + (size_t)tloc * NCHUNK * CAPB;

    for (int base = e0; base < e1; base += 64) {
        int i = base + lane;
        if (i < e1) {
            unsigned int s = (unsigned int)srcp[i];
            unsigned int d = (unsigned int)dstp[i];
            unsigned int ck = (unsigned int)(((unsigned long long)s * 1717987ull) >> 32); // s/2500
            unsigned int so = s - ck * NPC;
            unsigned int p = atomicAdd(&cur[wave][ck], 1u);   // p < 128 invariant
            stg[wave][ck][p] = (so << 17) | d;
        }
        unsigned int cnt = (lane < NCHUNK) ? cur[wave][lane] : 0u;
        unsigned long long mask = __ballot(cnt >= 64u);
        while (mask) {
            int ck = __ffsll((unsigned long long)mask) - 1;
            mask &= mask - 1;
            unsigned int n = cur[wave][ck];
            unsigned int gp = 0;
            if (lane == 0) gp = atomicAdd(&gc[ck], n);
            gp = (unsigned int)__shfl((int)gp, 0);
            if (gp + n <= CAPB) {
                for (unsigned int j = lane; j < n; j += 64)
                    bk[(size_t)ck * CAPB + gp + j] = stg[wave][ck][j];
            }
            if (lane == 0) cur[wave][ck] = 0u;
        }
    }
    // tail flush
    for (int ck = 0; ck < NCHUNK; ck++) {
        unsigned int n = cur[wave][ck];
        if (n > 0u) {
            unsigned int gp = 0;
            if (lane == 0) gp = atomicAdd(&gc[ck], n);
            gp = (unsigned int)__shfl((int)gp, 0);
            if (gp + n <= CAPB && lane < n)
                bk[(size_t)ck * CAPB + gp + lane] = stg[wave][ck][lane];
        }
    }
}

// ---------------------------------------------------------------------------
// Kernel 4 (fused): build a[src][b] chunk in LDS from bucket records, then
// stream the chunk's g rows. Emits DENSE per-chunk y partials (no atomics).
// grid (NCHUNK, tc). LDS 80 KB -> 2 blocks/CU.
// ---------------------------------------------------------------------------
__global__ __launch_bounds__(256) void k_scat(const float* __restrict__ g,
                                              const float* __restrict__ dinv,
                                              const unsigned int* __restrict__ buck,
                                              const unsigned int* __restrict__ gcur,
                                              float* __restrict__ yp, int t0) {
    __shared__ float a[NPC * BB];   // 80 KB
    int c = blockIdx.x, tloc = blockIdx.y, tg = t0 + tloc;
    for (int i = threadIdx.x; i < NPC * BB; i += 256) a[i] = 0.0f;
    __syncthreads();

    const float* dv = dinv + (size_t)tloc * MM;
    unsigned int n = gcur[tloc * NCHUNK + c];
    if (n > CAPB) n = CAPB;
    const unsigned int* bk = buck + ((size_t)tloc * NCHUNK + c) * CAPB;

    unsigned int n4 = n >> 2;
    for (unsigned int i = threadIdx.x; i < n4; i += 256) {
        uint4 r = ((const uint4*)bk)[i];
        unsigned int rec[4] = {r.x, r.y, r.z, r.w};
#pragma unroll
        for (int k = 0; k < 4; k++) {
            unsigned int d = rec[k] & 0x1FFFFu;
            unsigned int so = rec[k] >> 17;
            unsigned int b = (unsigned int)(((unsigned long long)d * 429497ull) >> 32); // d/10000
            atomicAdd(&a[so * BB + b], dv[d]);
        }
    }
    {
        unsigned int i = (n4 << 2) + threadIdx.x;
        if (i < n) {
            unsigned int rec = bk[i];
            unsigned int d = rec & 0x1FFFFu;
            unsigned int so = rec >> 17;
            unsigned int b = (unsigned int)(((unsigned long long)d * 429497ull) >> 32);
            atomicAdd(&a[so * BB + b], dv[d]);
        }
    }
    __syncthreads();

    // reduce phase: stream g rows for this chunk
    int lane = threadIdx.x & 63;
    int wave = threadIdx.x >> 6;
    int sub = lane >> 4;            // node within group of 4
    int f0 = (lane & 15) << 2;      // float4 feature base
    int b_c = c >> 2;               // batch of every node in this chunk
    const size_t base_g = ((size_t)(b_c * TT + tg) * NNODE + (size_t)(c & 3) * NPC) * FF;
    const float* dvc = dv + (size_t)c * NPC;

    float acc[BB][4];
#pragma unroll
    for (int b = 0; b < BB; b++)
#pragma unroll
        for (int q = 0; q < 4; q++) acc[b][q] = 0.0f;

    for (int gi = wave; gi < NPC / 4; gi += 4) {
        int joff = gi * 4 + sub;
        float dvj = dvc[joff];
        const float4 g4 = *(const float4*)(g + base_g + (size_t)joff * FF + f0);
        const float4 a0 = *(const float4*)(&a[joff * BB]);
        const float4 a1 = *(const float4*)(&a[joff * BB + 4]);
        float av[BB] = {a0.x, a0.y, a0.z, a0.w, a1.x, a1.y, a1.z, a1.w};
        float wv[BB];
#pragma unroll
        for (int b = 0; b < BB; b++)
            wv[b] = dvj * (av[b] + (b == b_c ? dvj : 0.0f));
#pragma unroll
        for (int b = 0; b < BB; b++) {
            acc[b][0] = fmaf(g4.x, wv[b], acc[b][0]);
            acc[b][1] = fmaf(g4.y, wv[b], acc[b][1]);
            acc[b][2] = fmaf(g4.z, wv[b], acc[b][2]);
            acc[b][3] = fmaf(g4.w, wv[b], acc[b][3]);
        }
    }

    __syncthreads();  // all a-reads done; reuse a[] as reduction scratch
#pragma unroll
    for (int b = 0; b < BB; b++)
#pragma unroll
        for (int q = 0; q < 4; q++) {
            float v = acc[b][q];
            v += __shfl_xor(v, 16);
            v += __shfl_xor(v, 32);
            acc[b][q] = v;
        }
    if (sub == 0) {
#pragma unroll
        for (int b = 0; b < BB; b++)
#pragma unroll
            for (int q = 0; q < 4; q++)
                a[wave * (BB * FF) + b * FF + f0 + q] = acc[b][q];
    }
    __syncthreads();
    for (int idx = threadIdx.x; idx < BB * FF; idx += 256) {
        float s = a[idx] + a[BB * FF + idx] + a[2 * BB * FF + idx] + a[3 * BB * FF + idx];
        yp[((size_t)tg * NCHUNK + c) * (BB * FF) + idx] = s;   // dense partial
    }
}

// ---------------------------------------------------------------------------
// Kernel 5: fold chunk partials + pooled projection + LSTM + FC.
// One block per batch element.
// ---------------------------------------------------------------------------
__global__ __launch_bounds__(256) void k_lstm(const float* __restrict__ yp,
                                              const float* __restrict__ Wg,
                                              const float* __restrict__ bg,
                                              const float* __restrict__ Wih,
                                              const float* __restrict__ Whh,
                                              const float* __restrict__ bih,
                                              const float* __restrict__ bhh,
                                              const float* __restrict__ Wfc,
                                              const float* __restrict__ bfc,
                                              float* __restrict__ out) {
    int b = blockIdx.x;
    int r = threadIdx.x;

    __shared__ float ys[TT][FF];
    __shared__ float xs[TT][HH];
    __shared__ float hs[HH], cs[HH], zs[4 * HH];

    // fold 32 chunk partials: ys[t][f] = sum_c yp[t][c][b][f]
    for (int idx = r; idx < TT * FF; idx += 256) {
        int t = idx >> 6, f = idx & 63;
        const float* p = yp + ((size_t)t * NCHUNK * BB + b) * FF + f;
        float s = 0.0f;
#pragma unroll
        for (int c = 0; c < NCHUNK; c++) s += p[(size_t)c * BB * FF];
        ys[t][f] = s;
    }
    __syncthreads();

    // pooled[t][h] = (1/N) * sum_f ys[t][f] * Wg[f][h] + bg[h]
    for (int idx = r; idx < TT * HH; idx += 256) {
        int t = idx >> 6, h = idx & 63;
        float s = 0.0f;
#pragma unroll
        for (int f = 0; f < FF; f++) s = fmaf(ys[t][f], Wg[f * HH + h], s);
        xs[t][h] = s * (1.0f / NNODE) + bg[h];
    }

    float wih[HH], whh[HH];
#pragma unroll
    for (int k = 0; k < HH; k++) {
        wih[k] = Wih[r * HH + k];
        whh[k] = Whh[r * HH + k];
    }
    float bias = bih[r] + bhh[r];

    if (r < HH) { hs[r] = 0.0f; cs[r] = 0.0f; }
    __syncthreads();

    for (int t = 0; t < TT; t++) {
        float acc = bias;
#pragma unroll
        for (int k = 0; k < HH; k++)
            acc = fmaf(wih[k], xs[t][k], fmaf(whh[k], hs[k], acc));
        zs[r] = acc;
        __syncthreads();
        if (r < HH) {
            float iv = zs[r], fv = zs[HH + r], gv = zs[2 * HH + r], ov = zs[3 * HH + r];
            float si = 1.0f / (1.0f + expf(-iv));
            float sf = 1.0f / (1.0f + expf(-fv));
            float so = 1.0f / (1.0f + expf(-ov));
            float cc = sf * cs[r] + si * tanhf(gv);
            cs[r] = cc;
            hs[r] = so * tanhf(cc);
        }
        __syncthreads();
    }

    if (r < NCLS) {
        float s = bfc[r];
#pragma unroll
        for (int k = 0; k < HH; k++) s = fmaf(hs[k], Wfc[r * HH + k], s);
        out[b * NCLS + r] = s;
    }
}

// ---------------------------------------------------------------------------
extern "C" void kernel_launch(void* const* d_in, const int* in_sizes, int n_in,
                              void* d_out, int out_size, void* d_ws, size_t ws_size,
                              hipStream_t stream) {
    const float* g   = (const float*)d_in[0];
    const int*   ei  = (const int*)d_in[1];
    const float* Wg  = (const float*)d_in[2];
    const float* bg  = (const float*)d_in[3];
    const float* Wih = (const float*)d_in[4];
    const float* Whh = (const float*)d_in[5];
    const float* bih = (const float*)d_in[6];
    const float* bhh = (const float*)d_in[7];
    const float* Wfc = (const float*)d_in[8];
    const float* bfc = (const float*)d_in[9];
    float* out = (float*)d_out;

    char* ws = (char*)d_ws;
    float* yp = (float*)ws;                               // [T][NCHUNK][B][F] partials
    const size_t ypBytes = (size_t)TT * NCHUNK * BB * FF * sizeof(float);  // 1 MB

    const size_t sz_dinv = (size_t)MM * 4;                // 320 KB
    const size_t sz_part = (size_t)NSEG_H * HW * 4;       // 1.28 MB
    const size_t sz_buck = (size_t)NCHUNK * CAPB * 4;     // 4.61 MB
    const size_t sz_gcur = (size_t)NCHUNK * 4;
    const size_t per_t = sz_dinv + sz_part + sz_buck + sz_gcur;

    size_t avail = (ws_size > ypBytes) ? ws_size - ypBytes : 0;
    int Tg = (int)(avail / per_t);
    if (Tg > TT) Tg = TT;
    if (Tg < 1) Tg = 1;

    float* dinv        = (float*)(ws + ypBytes);
    unsigned int* part = (unsigned int*)(ws + ypBytes + (size_t)Tg * sz_dinv);
    unsigned int* buck = (unsigned int*)(ws + ypBytes + (size_t)Tg * (sz_dinv + sz_part));
    unsigned int* gcur = (unsigned int*)(ws + ypBytes + (size_t)Tg * (sz_dinv + sz_part + sz_buck));

    for (int t0 = 0; t0 < TT; t0 += Tg) {
        int tc = (TT - t0 < Tg) ? (TT - t0) : Tg;
        hipMemsetAsync(gcur, 0, (size_t)tc * NCHUNK * 4, stream);

        dim3 gh(NSEG_H, tc);
        k_hist<<<gh, 256, 0, stream>>>(ei, part, t0);

        dim3 gm((HW + 255) / 256, tc);
        k_mdeg<<<gm, 256, 0, stream>>>(part, dinv);

        dim3 gp(NSEG_B, tc);
        k_part<<<gp, 256, 0, stream>>>(ei, buck, gcur, t0);

        dim3 gs(NCHUNK, tc);
        k_scat<<<gs, 256, 0, stream>>>(g, dinv, buck, gcur, yp, t0);
    }

    k_lstm<<<BB, 256, 0, stream>>>(yp, Wg, bg, Wih, Whh, bih, bhh, Wfc, bfc, out);
}

// Round 4
// 372.161 us; speedup vs baseline: 4.5222x; 1.2682x over previous
//
#include <hip/hip_runtime.h>
#include <hip/hip_bf16.h>

// Problem constants
#define BB 8
#define TT 16
#define NNODE 10000
#define FF 64
#define HH 64
#define EE 1000000
#define MM 80000      // BB * NNODE
#define NCLS 3

#define NCHUNK 32     // src chunks per timestep
#define NPC 2500      // nodes per chunk (NCHUNK*NPC == MM)
#define CAPB 36032    // bucket capacity (expected 31250, sigma~174; 64-aligned)
#define NSEG_H 16     // histogram edge segments (62500 edges each, uint4-divisible)
#define HW 20000      // histogram words (u8-packed: 4 bins/word = 80000 bins)
#define NSEG_B 32     // k_part blocks per timestep (x4 waves = 128 wave-segments/t)
#define EPW 7816      // edges per wave-segment (mult of 8; 128*7816 >= 1e6)
#define WCAP 144      // wave-private staging capacity per chunk
#define FLUSH_THR 96  // flush when staged count >= this
#define GPAD 16       // gcur padding: one cursor per 64B cacheline

// ---------------------------------------------------------------------------
// Kernel 1: per-timestep dst histogram, LDS-privatized, u8-packed, uint4 loads.
// ---------------------------------------------------------------------------
__global__ __launch_bounds__(256) void k_hist(const int* __restrict__ ei,
                                              unsigned int* __restrict__ part, int t0) {
    __shared__ unsigned int h[HW];   // 80 KB
    int seg = blockIdx.x, tloc = blockIdx.y, tg = t0 + tloc;
    for (int i = threadIdx.x; i < HW; i += 256) h[i] = 0u;
    __syncthreads();
    const uint4* dstp = (const uint4*)(ei + (size_t)tg * 2 * EE + EE
                                       + (size_t)seg * (EE / NSEG_H));
    for (int i = threadIdx.x; i < (EE / NSEG_H) / 4; i += 256) {
        uint4 d4 = dstp[i];
        atomicAdd(&h[d4.x >> 2], 1u << ((d4.x & 3u) * 8u));
        atomicAdd(&h[d4.y >> 2], 1u << ((d4.y & 3u) * 8u));
        atomicAdd(&h[d4.z >> 2], 1u << ((d4.z & 3u) * 8u));
        atomicAdd(&h[d4.w >> 2], 1u << ((d4.w & 3u) * 8u));
    }
    __syncthreads();
    unsigned int* outp = part + ((size_t)tloc * NSEG_H + seg) * HW;
    for (int i = threadIdx.x; i < HW; i += 256) outp[i] = h[i];
}

// ---------------------------------------------------------------------------
// Kernel 2: merge histogram partials -> dinv = rsqrt(deg+1).
// ---------------------------------------------------------------------------
__global__ __launch_bounds__(256) void k_mdeg(const unsigned int* __restrict__ part,
                                              float* __restrict__ dinv) {
    int w = blockIdx.x * 256 + threadIdx.x;
    int tloc = blockIdx.y;
    if (w >= HW) return;
    const unsigned int* p = part + (size_t)tloc * NSEG_H * HW;
    unsigned int s = 0;
#pragma unroll
    for (int k = 0; k < NSEG_H; k++) s += p[(size_t)k * HW + w];
    float4 r;
    r.x = rsqrtf((float)(s & 255u) + 1.0f);
    r.y = rsqrtf((float)((s >> 8) & 255u) + 1.0f);
    r.z = rsqrtf((float)((s >> 16) & 255u) + 1.0f);
    r.w = rsqrtf((float)((s >> 24) & 255u) + 1.0f);
    *(float4*)(dinv + (size_t)tloc * MM + (size_t)w * 4) = r;
}

// ---------------------------------------------------------------------------
// Kernel 3: barrier-free edge partition, 4 edges/lane/iter, padded cursors.
// Record = (src_off<<17)|dst. grid (NSEG_B, tc), 4 waves/block.
// ---------------------------------------------------------------------------
__global__ __launch_bounds__(256) void k_part(const int* __restrict__ ei,
                                              unsigned int* __restrict__ buck,
                                              unsigned int* __restrict__ gcur, int t0) {
    __shared__ unsigned int stg[4][NCHUNK][WCAP];   // 72 KB
    __shared__ unsigned int cur[4][NCHUNK];         // 512 B
    int wave = threadIdx.x >> 6, lane = threadIdx.x & 63;
    int tloc = blockIdx.y, tg = t0 + tloc;
    if (lane < NCHUNK) cur[wave][lane] = 0u;        // wave-private init, no barrier

    int wseg = blockIdx.x * 4 + wave;               // wave-segment id within t
    int e0 = wseg * EPW;
    int e1 = e0 + EPW; if (e1 > EE) e1 = EE;
    const uint4* src4 = (const uint4*)(ei + (size_t)tg * 2 * EE);
    const uint4* dst4 = (const uint4*)(ei + (size_t)tg * 2 * EE + EE);
    unsigned int* gc = gcur + (size_t)tloc * NCHUNK * GPAD;
    unsigned int* bk = buck + (size_t)tloc * NCHUNK * CAPB;

    int i40 = e0 >> 2, i41 = e1 >> 2;
    int nIter = (i41 - i40 + 63) >> 6;              // wave-uniform
    for (int k = 0; k < nIter; k++) {
        int i4 = i40 + k * 64 + lane;
        if (i4 < i41) {
            uint4 s4 = src4[i4];
            uint4 d4 = dst4[i4];
            unsigned int ss[4] = {s4.x, s4.y, s4.z, s4.w};
            unsigned int dd[4] = {d4.x, d4.y, d4.z, d4.w};
#pragma unroll
            for (int j = 0; j < 4; j++) {
                unsigned int ck = (unsigned int)(((unsigned long long)ss[j] * 1717987ull) >> 32); // /2500
                unsigned int so = ss[j] - ck * NPC;
                unsigned int p = atomicAdd(&cur[wave][ck], 1u);
                if (p < WCAP) stg[wave][ck][p] = (so << 17) | dd[j];
            }
        }
        unsigned int cnt = (lane < NCHUNK) ? cur[wave][lane] : 0u;
        unsigned long long mask = __ballot(cnt >= FLUSH_THR);
        while (mask) {
            int ck = __ffsll((unsigned long long)mask) - 1;
            mask &= mask - 1;
            unsigned int n = cur[wave][ck];
            if (n > WCAP) n = WCAP;
            unsigned int gp = 0;
            if (lane == 0) gp = atomicAdd(&gc[ck * GPAD], n);
            gp = (unsigned int)__shfl((int)gp, 0);
            if (gp + n <= CAPB) {
                for (unsigned int j = lane; j < n; j += 64)
                    bk[(size_t)ck * CAPB + gp + j] = stg[wave][ck][j];
            }
            if (lane == 0) cur[wave][ck] = 0u;
        }
    }
    // tail flush
    for (int ck = 0; ck < NCHUNK; ck++) {
        unsigned int n = cur[wave][ck];
        if (n > WCAP) n = WCAP;
        if (n > 0u) {
            unsigned int gp = 0;
            if (lane == 0) gp = atomicAdd(&gc[ck * GPAD], n);
            gp = (unsigned int)__shfl((int)gp, 0);
            if (gp + n <= CAPB) {
                for (unsigned int j = lane; j < n; j += 64)
                    bk[(size_t)ck * CAPB + gp + j] = stg[wave][ck][j];
            }
        }
    }
}

// ---------------------------------------------------------------------------
// Kernel 4 (fused): build a[src][b] chunk in LDS from bucket records, then
// stream the chunk's g rows. Emits DENSE per-chunk y partials (no atomics).
// grid (NCHUNK, tc). LDS 80 KB -> 2 blocks/CU.
// ---------------------------------------------------------------------------
__global__ __launch_bounds__(256) void k_scat(const float* __restrict__ g,
                                              const float* __restrict__ dinv,
                                              const unsigned int* __restrict__ buck,
                                              const unsigned int* __restrict__ gcur,
                                              float* __restrict__ yp, int t0) {
    __shared__ float a[NPC * BB];   // 80 KB
    int c = blockIdx.x, tloc = blockIdx.y, tg = t0 + tloc;
    for (int i = threadIdx.x; i < NPC * BB; i += 256) a[i] = 0.0f;
    __syncthreads();

    const float* dv = dinv + (size_t)tloc * MM;
    unsigned int n = gcur[((size_t)tloc * NCHUNK + c) * GPAD];
    if (n > CAPB) n = CAPB;
    const unsigned int* bk = buck + ((size_t)tloc * NCHUNK + c) * CAPB;

    unsigned int n4 = n >> 2;
    for (unsigned int i = threadIdx.x; i < n4; i += 256) {
        uint4 r = ((const uint4*)bk)[i];
        unsigned int rec[4] = {r.x, r.y, r.z, r.w};
#pragma unroll
        for (int k = 0; k < 4; k++) {
            unsigned int d = rec[k] & 0x1FFFFu;
            unsigned int so = rec[k] >> 17;
            unsigned int b = (unsigned int)(((unsigned long long)d * 429497ull) >> 32); // /10000
            atomicAdd(&a[so * BB + b], dv[d]);
        }
    }
    {
        unsigned int i = (n4 << 2) + threadIdx.x;
        if (i < n) {
            unsigned int rec = bk[i];
            unsigned int d = rec & 0x1FFFFu;
            unsigned int so = rec >> 17;
            unsigned int b = (unsigned int)(((unsigned long long)d * 429497ull) >> 32);
            atomicAdd(&a[so * BB + b], dv[d]);
        }
    }
    __syncthreads();

    // reduce phase: stream g rows for this chunk
    int lane = threadIdx.x & 63;
    int wave = threadIdx.x >> 6;
    int sub = lane >> 4;            // node within group of 4
    int f0 = (lane & 15) << 2;      // float4 feature base
    int b_c = c >> 2;               // batch of every node in this chunk
    const size_t base_g = ((size_t)(b_c * TT + tg) * NNODE + (size_t)(c & 3) * NPC) * FF;
    const float* dvc = dv + (size_t)c * NPC;

    float acc[BB][4];
#pragma unroll
    for (int b = 0; b < BB; b++)
#pragma unroll
        for (int q = 0; q < 4; q++) acc[b][q] = 0.0f;

    for (int gi = wave; gi < NPC / 4; gi += 4) {
        int joff = gi * 4 + sub;
        float dvj = dvc[joff];
        const float4 g4 = *(const float4*)(g + base_g + (size_t)joff * FF + f0);
        const float4 a0 = *(const float4*)(&a[joff * BB]);
        const float4 a1 = *(const float4*)(&a[joff * BB + 4]);
        float av[BB] = {a0.x, a0.y, a0.z, a0.w, a1.x, a1.y, a1.z, a1.w};
        float wv[BB];
#pragma unroll
        for (int b = 0; b < BB; b++)
            wv[b] = dvj * (av[b] + (b == b_c ? dvj : 0.0f));
#pragma unroll
        for (int b = 0; b < BB; b++) {
            acc[b][0] = fmaf(g4.x, wv[b], acc[b][0]);
            acc[b][1] = fmaf(g4.y, wv[b], acc[b][1]);
            acc[b][2] = fmaf(g4.z, wv[b], acc[b][2]);
            acc[b][3] = fmaf(g4.w, wv[b], acc[b][3]);
        }
    }

    __syncthreads();  // all a-reads done; reuse a[] as reduction scratch
#pragma unroll
    for (int b = 0; b < BB; b++)
#pragma unroll
        for (int q = 0; q < 4; q++) {
            float v = acc[b][q];
            v += __shfl_xor(v, 16);
            v += __shfl_xor(v, 32);
            acc[b][q] = v;
        }
    if (sub == 0) {
#pragma unroll
        for (int b = 0; b < BB; b++)
#pragma unroll
            for (int q = 0; q < 4; q++)
                a[wave * (BB * FF) + b * FF + f0 + q] = acc[b][q];
    }
    __syncthreads();
    for (int idx = threadIdx.x; idx < BB * FF; idx += 256) {
        float s = a[idx] + a[BB * FF + idx] + a[2 * BB * FF + idx] + a[3 * BB * FF + idx];
        yp[((size_t)tg * NCHUNK + c) * (BB * FF) + idx] = s;   // dense partial
    }
}

// ---------------------------------------------------------------------------
// Kernel 5: fold chunk partials + pooled projection + LSTM + FC.
// ---------------------------------------------------------------------------
__global__ __launch_bounds__(256) void k_lstm(const float* __restrict__ yp,
                                              const float* __restrict__ Wg,
                                              const float* __restrict__ bg,
                                              const float* __restrict__ Wih,
                                              const float* __restrict__ Whh,
                                              const float* __restrict__ bih,
                                              const float* __restrict__ bhh,
                                              const float* __restrict__ Wfc,
                                              const float* __restrict__ bfc,
                                              float* __restrict__ out) {
    int b = blockIdx.x;
    int r = threadIdx.x;

    __shared__ float ys[TT][FF];
    __shared__ float xs[TT][HH];
    __shared__ float hs[HH], cs[HH], zs[4 * HH];

    for (int idx = r; idx < TT * FF; idx += 256) {
        int t = idx >> 6, f = idx & 63;
        const float* p = yp + ((size_t)t * NCHUNK * BB + b) * FF + f;
        float s = 0.0f;
#pragma unroll
        for (int c = 0; c < NCHUNK; c++) s += p[(size_t)c * BB * FF];
        ys[t][f] = s;
    }
    __syncthreads();

    for (int idx = r; idx < TT * HH; idx += 256) {
        int t = idx >> 6, h = idx & 63;
        float s = 0.0f;
#pragma unroll
        for (int f = 0; f < FF; f++) s = fmaf(ys[t][f], Wg[f * HH + h], s);
        xs[t][h] = s * (1.0f / NNODE) + bg[h];
    }

    float wih[HH], whh[HH];
#pragma unroll
    for (int k = 0; k < HH; k++) {
        wih[k] = Wih[r * HH + k];
        whh[k] = Whh[r * HH + k];
    }
    float bias = bih[r] + bhh[r];

    if (r < HH) { hs[r] = 0.0f; cs[r] = 0.0f; }
    __syncthreads();

    for (int t = 0; t < TT; t++) {
        float acc = bias;
#pragma unroll
        for (int k = 0; k < HH; k++)
            acc = fmaf(wih[k], xs[t][k], fmaf(whh[k], hs[k], acc));
        zs[r] = acc;
        __syncthreads();
        if (r < HH) {
            float iv = zs[r], fv = zs[HH + r], gv = zs[2 * HH + r], ov = zs[3 * HH + r];
            float si = 1.0f / (1.0f + expf(-iv));
            float sf = 1.0f / (1.0f + expf(-fv));
            float so = 1.0f / (1.0f + expf(-ov));
            float cc = sf * cs[r] + si * tanhf(gv);
            cs[r] = cc;
            hs[r] = so * tanhf(cc);
        }
        __syncthreads();
    }

    if (r < NCLS) {
        float s = bfc[r];
#pragma unroll
        for (int k = 0; k < HH; k++) s = fmaf(hs[k], Wfc[r * HH + k], s);
        out[b * NCLS + r] = s;
    }
}

// ---------------------------------------------------------------------------
extern "C" void kernel_launch(void* const* d_in, const int* in_sizes, int n_in,
                              void* d_out, int out_size, void* d_ws, size_t ws_size,
                              hipStream_t stream) {
    const float* g   = (const float*)d_in[0];
    const int*   ei  = (const int*)d_in[1];
    const float* Wg  = (const float*)d_in[2];
    const float* bg  = (const float*)d_in[3];
    const float* Wih = (const float*)d_in[4];
    const float* Whh = (const float*)d_in[5];
    const float* bih = (const float*)d_in[6];
    const float* bhh = (const float*)d_in[7];
    const float* Wfc = (const float*)d_in[8];
    const float* bfc = (const float*)d_in[9];
    float* out = (float*)d_out;

    char* ws = (char*)d_ws;
    float* yp = (float*)ws;                               // [T][NCHUNK][B][F] partials
    const size_t ypBytes = (size_t)TT * NCHUNK * BB * FF * sizeof(float);  // 1 MB

    const size_t sz_dinv = (size_t)MM * 4;                // 320 KB
    const size_t sz_part = (size_t)NSEG_H * HW * 4;       // 1.28 MB
    const size_t sz_buck = (size_t)NCHUNK * CAPB * 4;     // 4.61 MB
    const size_t sz_gcur = (size_t)NCHUNK * GPAD * 4;     // 2 KB
    const size_t per_t = sz_dinv + sz_part + sz_buck + sz_gcur;

    size_t avail = (ws_size > ypBytes) ? ws_size - ypBytes : 0;
    int Tg = (int)(avail / per_t);
    if (Tg > TT) Tg = TT;
    if (Tg < 1) Tg = 1;

    float* dinv        = (float*)(ws + ypBytes);
    unsigned int* part = (unsigned int*)(ws + ypBytes + (size_t)Tg * sz_dinv);
    unsigned int* buck = (unsigned int*)(ws + ypBytes + (size_t)Tg * (sz_dinv + sz_part));
    unsigned int* gcur = (unsigned int*)(ws + ypBytes + (size_t)Tg * (sz_dinv + sz_part + sz_buck));

    for (int t0 = 0; t0 < TT; t0 += Tg) {
        int tc = (TT - t0 < Tg) ? (TT - t0) : Tg;
        hipMemsetAsync(gcur, 0, (size_t)tc * NCHUNK * GPAD * 4, stream);

        dim3 gh(NSEG_H, tc);
        k_hist<<<gh, 256, 0, stream>>>(ei, part, t0);

        dim3 gm((HW + 255) / 256, tc);
        k_mdeg<<<gm, 256, 0, stream>>>(part, dinv);

        dim3 gp(NSEG_B, tc);
        k_part<<<gp, 256, 0, stream>>>(ei, buck, gcur, t0);

        dim3 gs(NCHUNK, tc);
        k_scat<<<gs, 256, 0, stream>>>(g, dinv, buck, gcur, yp, t0);
    }

    k_lstm<<<BB, 256, 0, stream>>>(yp, Wg, bg, Wih, Whh, bih, bhh, Wfc, bfc, out);
}

// Round 5
// 341.785 us; speedup vs baseline: 4.9241x; 1.0889x over previous
//
#include <hip/hip_runtime.h>
#include <hip/hip_bf16.h>

// Problem constants
#define BB 8
#define TT 16
#define NNODE 10000
#define FF 64
#define HH 64
#define EE 1000000
#define MM 80000      // BB * NNODE
#define NCLS 3

#define NCHUNK 32     // src chunks per timestep
#define NPC 2500      // nodes per chunk (NCHUNK*NPC == MM)
#define CAPB 36032    // bucket capacity (expected 31250, sigma~174; 64-aligned)
#define NSEG_H 16     // histogram edge segments (62500 edges each, uint4-divisible)
#define HW 20000      // histogram words (u8-packed: 4 bins/word = 80000 bins)
#define NSEG_B 32     // k_part blocks per timestep (x4 waves = 128 wave-segments/t)
#define EPW 7816      // edges per wave-segment (mult of 8; 128*7816 >= 1e6)
#define WCAP 144      // wave-private staging capacity per chunk
#define FLUSH_THR 96  // flush when staged count >= this
#define GPAD 16       // gcur padding: one cursor per 64B cacheline

// ---------------------------------------------------------------------------
// Kernel 1: per-timestep dst histogram, LDS-privatized, u8-packed, uint4 loads.
// ---------------------------------------------------------------------------
__global__ __launch_bounds__(256) void k_hist(const int* __restrict__ ei,
                                              unsigned int* __restrict__ part, int t0) {
    __shared__ unsigned int h[HW];   // 80 KB
    int seg = blockIdx.x, tloc = blockIdx.y, tg = t0 + tloc;
    for (int i = threadIdx.x; i < HW; i += 256) h[i] = 0u;
    __syncthreads();
    const uint4* dstp = (const uint4*)(ei + (size_t)tg * 2 * EE + EE
                                       + (size_t)seg * (EE / NSEG_H));
    for (int i = threadIdx.x; i < (EE / NSEG_H) / 4; i += 256) {
        uint4 d4 = dstp[i];
        atomicAdd(&h[d4.x >> 2], 1u << ((d4.x & 3u) * 8u));
        atomicAdd(&h[d4.y >> 2], 1u << ((d4.y & 3u) * 8u));
        atomicAdd(&h[d4.z >> 2], 1u << ((d4.z & 3u) * 8u));
        atomicAdd(&h[d4.w >> 2], 1u << ((d4.w & 3u) * 8u));
    }
    __syncthreads();
    unsigned int* outp = part + ((size_t)tloc * NSEG_H + seg) * HW;
    for (int i = threadIdx.x; i < HW; i += 256) outp[i] = h[i];
}

// ---------------------------------------------------------------------------
// Kernel 2: merge histogram partials -> dinv = rsqrt(deg+1).
// ---------------------------------------------------------------------------
__global__ __launch_bounds__(256) void k_mdeg(const unsigned int* __restrict__ part,
                                              float* __restrict__ dinv) {
    int w = blockIdx.x * 256 + threadIdx.x;
    int tloc = blockIdx.y;
    if (w >= HW) return;
    const unsigned int* p = part + (size_t)tloc * NSEG_H * HW;
    unsigned int s = 0;
#pragma unroll
    for (int k = 0; k < NSEG_H; k++) s += p[(size_t)k * HW + w];
    float4 r;
    r.x = rsqrtf((float)(s & 255u) + 1.0f);
    r.y = rsqrtf((float)((s >> 8) & 255u) + 1.0f);
    r.z = rsqrtf((float)((s >> 16) & 255u) + 1.0f);
    r.w = rsqrtf((float)((s >> 24) & 255u) + 1.0f);
    *(float4*)(dinv + (size_t)tloc * MM + (size_t)w * 4) = r;
}

// ---------------------------------------------------------------------------
// Kernel 3: barrier-free edge partition, 4 edges/lane/iter, padded cursors.
// Record = (src_off<<17)|dst. grid (NSEG_B, tc), 4 waves/block.
// ---------------------------------------------------------------------------
__global__ __launch_bounds__(256) void k_part(const int* __restrict__ ei,
                                              unsigned int* __restrict__ buck,
                                              unsigned int* __restrict__ gcur, int t0) {
    __shared__ unsigned int stg[4][NCHUNK][WCAP];   // 72 KB
    __shared__ unsigned int cur[4][NCHUNK];         // 512 B
    int wave = threadIdx.x >> 6, lane = threadIdx.x & 63;
    int tloc = blockIdx.y, tg = t0 + tloc;
    if (lane < NCHUNK) cur[wave][lane] = 0u;        // wave-private init, no barrier

    int wseg = blockIdx.x * 4 + wave;               // wave-segment id within t
    int e0 = wseg * EPW;
    int e1 = e0 + EPW; if (e1 > EE) e1 = EE;
    const uint4* src4 = (const uint4*)(ei + (size_t)tg * 2 * EE);
    const uint4* dst4 = (const uint4*)(ei + (size_t)tg * 2 * EE + EE);
    unsigned int* gc = gcur + (size_t)tloc * NCHUNK * GPAD;
    unsigned int* bk = buck + (size_t)tloc * NCHUNK * CAPB;

    int i40 = e0 >> 2, i41 = e1 >> 2;
    int nIter = (i41 - i40 + 63) >> 6;              // wave-uniform
    for (int k = 0; k < nIter; k++) {
        int i4 = i40 + k * 64 + lane;
        if (i4 < i41) {
            uint4 s4 = src4[i4];
            uint4 d4 = dst4[i4];
            unsigned int ss[4] = {s4.x, s4.y, s4.z, s4.w};
            unsigned int dd[4] = {d4.x, d4.y, d4.z, d4.w};
#pragma unroll
            for (int j = 0; j < 4; j++) {
                unsigned int ck = (unsigned int)(((unsigned long long)ss[j] * 1717987ull) >> 32); // /2500
                unsigned int so = ss[j] - ck * NPC;
                unsigned int p = atomicAdd(&cur[wave][ck], 1u);
                if (p < WCAP) stg[wave][ck][p] = (so << 17) | dd[j];
            }
        }
        unsigned int cnt = (lane < NCHUNK) ? cur[wave][lane] : 0u;
        unsigned long long mask = __ballot(cnt >= FLUSH_THR);
        while (mask) {
            int ck = __ffsll((unsigned long long)mask) - 1;
            mask &= mask - 1;
            unsigned int n = cur[wave][ck];
            if (n > WCAP) n = WCAP;
            unsigned int gp = 0;
            if (lane == 0) gp = atomicAdd(&gc[ck * GPAD], n);
            gp = (unsigned int)__shfl((int)gp, 0);
            if (gp + n <= CAPB) {
                for (unsigned int j = lane; j < n; j += 64)
                    bk[(size_t)ck * CAPB + gp + j] = stg[wave][ck][j];
            }
            if (lane == 0) cur[wave][ck] = 0u;
        }
    }
    // tail flush
    for (int ck = 0; ck < NCHUNK; ck++) {
        unsigned int n = cur[wave][ck];
        if (n > WCAP) n = WCAP;
        if (n > 0u) {
            unsigned int gp = 0;
            if (lane == 0) gp = atomicAdd(&gc[ck * GPAD], n);
            gp = (unsigned int)__shfl((int)gp, 0);
            if (gp + n <= CAPB) {
                for (unsigned int j = lane; j < n; j += 64)
                    bk[(size_t)ck * CAPB + gp + j] = stg[wave][ck][j];
            }
        }
    }
}

// ---------------------------------------------------------------------------
// Kernel 4 (fused): build a[src][b] chunk in LDS from bucket records, then
// stream the chunk's g rows. Emits DENSE per-chunk y partials (no atomics).
// grid (NCHUNK, tc), 512 threads (8 waves). LDS 80 KB -> 2 blocks/CU,
// 16 waves/CU. Reduce loop unrolled x2 (>=2 outstanding 1KB loads/wave).
// ---------------------------------------------------------------------------
__global__ __launch_bounds__(512) void k_scat(const float* __restrict__ g,
                                              const float* __restrict__ dinv,
                                              const unsigned int* __restrict__ buck,
                                              const unsigned int* __restrict__ gcur,
                                              float* __restrict__ yp, int t0) {
    __shared__ float a[NPC * BB];   // 80 KB
    int c = blockIdx.x, tloc = blockIdx.y, tg = t0 + tloc;
    for (int i = threadIdx.x; i < NPC * BB; i += 512) a[i] = 0.0f;
    __syncthreads();

    const float* dv = dinv + (size_t)tloc * MM;
    unsigned int n = gcur[((size_t)tloc * NCHUNK + c) * GPAD];
    if (n > CAPB) n = CAPB;
    const unsigned int* bk = buck + ((size_t)tloc * NCHUNK + c) * CAPB;

    unsigned int n4 = n >> 2;
    for (unsigned int i = threadIdx.x; i < n4; i += 512) {
        uint4 r = ((const uint4*)bk)[i];
        unsigned int rec[4] = {r.x, r.y, r.z, r.w};
#pragma unroll
        for (int k = 0; k < 4; k++) {
            unsigned int d = rec[k] & 0x1FFFFu;
            unsigned int so = rec[k] >> 17;
            unsigned int b = (unsigned int)(((unsigned long long)d * 429497ull) >> 32); // /10000
            atomicAdd(&a[so * BB + b], dv[d]);
        }
    }
    {
        unsigned int i = (n4 << 2) + threadIdx.x;
        if (i < n) {
            unsigned int rec = bk[i];
            unsigned int d = rec & 0x1FFFFu;
            unsigned int so = rec >> 17;
            unsigned int b = (unsigned int)(((unsigned long long)d * 429497ull) >> 32);
            atomicAdd(&a[so * BB + b], dv[d]);
        }
    }
    __syncthreads();

    // reduce phase: stream g rows for this chunk. 8 waves, unroll x2.
    int lane = threadIdx.x & 63;
    int wave = threadIdx.x >> 6;          // 0..7
    int sub = lane >> 4;                  // node within group of 4
    int f0 = (lane & 15) << 2;            // float4 feature base
    int b_c = c >> 2;                     // batch of every node in this chunk
    const size_t base_g = ((size_t)(b_c * TT + tg) * NNODE + (size_t)(c & 3) * NPC) * FF;
    const float* dvc = dv + (size_t)c * NPC;

    float acc[BB][4];
#pragma unroll
    for (int b = 0; b < BB; b++)
#pragma unroll
        for (int q = 0; q < 4; q++) acc[b][q] = 0.0f;

    const int NG = NPC / 4;               // 625 groups of 4 rows
    for (int gi = wave; gi < NG; gi += 16) {
        int j0 = gi * 4 + sub;
        int gi1 = gi + 8;
        int j1 = gi1 * 4 + sub;
        bool has1 = (gi1 < NG);
        // issue both global loads first
        const float4 g40 = *(const float4*)(g + base_g + (size_t)j0 * FF + f0);
        float4 g41 = has1 ? *(const float4*)(g + base_g + (size_t)j1 * FF + f0)
                          : make_float4(0.f, 0.f, 0.f, 0.f);
        {
            float dvj = dvc[j0];
            const float4 a0 = *(const float4*)(&a[j0 * BB]);
            const float4 a1 = *(const float4*)(&a[j0 * BB + 4]);
            float av[BB] = {a0.x, a0.y, a0.z, a0.w, a1.x, a1.y, a1.z, a1.w};
#pragma unroll
            for (int b = 0; b < BB; b++) {
                float wv = dvj * (av[b] + (b == b_c ? dvj : 0.0f));
                acc[b][0] = fmaf(g40.x, wv, acc[b][0]);
                acc[b][1] = fmaf(g40.y, wv, acc[b][1]);
                acc[b][2] = fmaf(g40.z, wv, acc[b][2]);
                acc[b][3] = fmaf(g40.w, wv, acc[b][3]);
            }
        }
        if (has1) {
            float dvj = dvc[j1];
            const float4 a0 = *(const float4*)(&a[j1 * BB]);
            const float4 a1 = *(const float4*)(&a[j1 * BB + 4]);
            float av[BB] = {a0.x, a0.y, a0.z, a0.w, a1.x, a1.y, a1.z, a1.w};
#pragma unroll
            for (int b = 0; b < BB; b++) {
                float wv = dvj * (av[b] + (b == b_c ? dvj : 0.0f));
                acc[b][0] = fmaf(g41.x, wv, acc[b][0]);
                acc[b][1] = fmaf(g41.y, wv, acc[b][1]);
                acc[b][2] = fmaf(g41.z, wv, acc[b][2]);
                acc[b][3] = fmaf(g41.w, wv, acc[b][3]);
            }
        }
    }

    __syncthreads();  // all a-reads done; reuse a[] as reduction scratch
#pragma unroll
    for (int b = 0; b < BB; b++)
#pragma unroll
        for (int q = 0; q < 4; q++) {
            float v = acc[b][q];
            v += __shfl_xor(v, 16);
            v += __shfl_xor(v, 32);
            acc[b][q] = v;
        }
    if (sub == 0) {
#pragma unroll
        for (int b = 0; b < BB; b++)
#pragma unroll
            for (int q = 0; q < 4; q++)
                a[wave * (BB * FF) + b * FF + f0 + q] = acc[b][q];
    }
    __syncthreads();
    for (int idx = threadIdx.x; idx < BB * FF; idx += 512) {
        float s = 0.0f;
#pragma unroll
        for (int w = 0; w < 8; w++) s += a[w * (BB * FF) + idx];
        yp[((size_t)tg * NCHUNK + c) * (BB * FF) + idx] = s;   // dense partial
    }
}

// ---------------------------------------------------------------------------
// Kernel 5: fold chunk partials + pooled projection + LSTM + FC.
// ---------------------------------------------------------------------------
__global__ __launch_bounds__(256) void k_lstm(const float* __restrict__ yp,
                                              const float* __restrict__ Wg,
                                              const float* __restrict__ bg,
                                              const float* __restrict__ Wih,
                                              const float* __restrict__ Whh,
                                              const float* __restrict__ bih,
                                              const float* __restrict__ bhh,
                                              const float* __restrict__ Wfc,
                                              const float* __restrict__ bfc,
                                              float* __restrict__ out) {
    int b = blockIdx.x;
    int r = threadIdx.x;

    __shared__ float ys[TT][FF];
    __shared__ float xs[TT][HH];
    __shared__ float hs[HH], cs[HH], zs[4 * HH];

    for (int idx = r; idx < TT * FF; idx += 256) {
        int t = idx >> 6, f = idx & 63;
        const float* p = yp + ((size_t)t * NCHUNK * BB + b) * FF + f;
        float s = 0.0f;
#pragma unroll
        for (int c = 0; c < NCHUNK; c++) s += p[(size_t)c * BB * FF];
        ys[t][f] = s;
    }
    __syncthreads();

    for (int idx = r; idx < TT * HH; idx += 256) {
        int t = idx >> 6, h = idx & 63;
        float s = 0.0f;
#pragma unroll
        for (int f = 0; f < FF; f++) s = fmaf(ys[t][f], Wg[f * HH + h], s);
        xs[t][h] = s * (1.0f / NNODE) + bg[h];
    }

    float wih[HH], whh[HH];
#pragma unroll
    for (int k = 0; k < HH; k++) {
        wih[k] = Wih[r * HH + k];
        whh[k] = Whh[r * HH + k];
    }
    float bias = bih[r] + bhh[r];

    if (r < HH) { hs[r] = 0.0f; cs[r] = 0.0f; }
    __syncthreads();

    for (int t = 0; t < TT; t++) {
        float acc = bias;
#pragma unroll
        for (int k = 0; k < HH; k++)
            acc = fmaf(wih[k], xs[t][k], fmaf(whh[k], hs[k], acc));
        zs[r] = acc;
        __syncthreads();
        if (r < HH) {
            float iv = zs[r], fv = zs[HH + r], gv = zs[2 * HH + r], ov = zs[3 * HH + r];
            float si = 1.0f / (1.0f + expf(-iv));
            float sf = 1.0f / (1.0f + expf(-fv));
            float so = 1.0f / (1.0f + expf(-ov));
            float cc = sf * cs[r] + si * tanhf(gv);
            cs[r] = cc;
            hs[r] = so * tanhf(cc);
        }
        __syncthreads();
    }

    if (r < NCLS) {
        float s = bfc[r];
#pragma unroll
        for (int k = 0; k < HH; k++) s = fmaf(hs[k], Wfc[r * HH + k], s);
        out[b * NCLS + r] = s;
    }
}

// ---------------------------------------------------------------------------
extern "C" void kernel_launch(void* const* d_in, const int* in_sizes, int n_in,
                              void* d_out, int out_size, void* d_ws, size_t ws_size,
                              hipStream_t stream) {
    const float* g   = (const float*)d_in[0];
    const int*   ei  = (const int*)d_in[1];
    const float* Wg  = (const float*)d_in[2];
    const float* bg  = (const float*)d_in[3];
    const float* Wih = (const float*)d_in[4];
    const float* Whh = (const float*)d_in[5];
    const float* bih = (const float*)d_in[6];
    const float* bhh = (const float*)d_in[7];
    const float* Wfc = (const float*)d_in[8];
    const float* bfc = (const float*)d_in[9];
    float* out = (float*)d_out;

    char* ws = (char*)d_ws;
    float* yp = (float*)ws;                               // [T][NCHUNK][B][F] partials
    const size_t ypBytes = (size_t)TT * NCHUNK * BB * FF * sizeof(float);  // 1 MB

    const size_t sz_dinv = (size_t)MM * 4;                // 320 KB
    const size_t sz_part = (size_t)NSEG_H * HW * 4;       // 1.28 MB
    const size_t sz_buck = (size_t)NCHUNK * CAPB * 4;     // 4.61 MB
    const size_t sz_gcur = (size_t)NCHUNK * GPAD * 4;     // 2 KB
    const size_t per_t = sz_dinv + sz_part + sz_buck + sz_gcur;

    size_t avail = (ws_size > ypBytes) ? ws_size - ypBytes : 0;
    int Tg = (int)(avail / per_t);
    if (Tg > TT) Tg = TT;
    if (Tg < 1) Tg = 1;

    float* dinv        = (float*)(ws + ypBytes);
    unsigned int* part = (unsigned int*)(ws + ypBytes + (size_t)Tg * sz_dinv);
    unsigned int* buck = (unsigned int*)(ws + ypBytes + (size_t)Tg * (sz_dinv + sz_part));
    unsigned int* gcur = (unsigned int*)(ws + ypBytes + (size_t)Tg * (sz_dinv + sz_part + sz_buck));

    for (int t0 = 0; t0 < TT; t0 += Tg) {
        int tc = (TT - t0 < Tg) ? (TT - t0) : Tg;
        hipMemsetAsync(gcur, 0, (size_t)tc * NCHUNK * GPAD * 4, stream);

        dim3 gh(NSEG_H, tc);
        k_hist<<<gh, 256, 0, stream>>>(ei, part, t0);

        dim3 gm((HW + 255) / 256, tc);
        k_mdeg<<<gm, 256, 0, stream>>>(part, dinv);

        dim3 gp(NSEG_B, tc);
        k_part<<<gp, 256, 0, stream>>>(ei, buck, gcur, t0);

        dim3 gs(NCHUNK, tc);
        k_scat<<<gs, 512, 0, stream>>>(g, dinv, buck, gcur, yp, t0);
    }

    k_lstm<<<BB, 256, 0, stream>>>(yp, Wg, bg, Wih, Whh, bih, bhh, Wfc, bfc, out);
}